// Round 6
// baseline (254.853 us; speedup 1.0000x reference)
//
#include <hip/hip_runtime.h>
#include <math.h>

#define Bn 128
#define Sn 200
#define NC3n 4000
#define GRUB 32                 // 32 blocks x 4 rows = 128 GRU rows
#define FILLB 256               // (b, t-half): 256 contiguous 1.6MB streams

__device__ __forceinline__ float sigmf(float x) { return 1.f / (1.f + __expf(-x)); }
__device__ __forceinline__ float rlane(float v, int k) {
    return __int_as_float(__builtin_amdgcn_readlane(__float_as_int(v), k));
}

#define UPD(q, cbase) { int d = cc - (cbase); if ((unsigned)d < 4u) { \
    q.x = (d==0)?v:q.x; q.y = (d==1)?v:q.y; q.z = (d==2)?v:q.z; q.w = (d==3)?v:q.w; } }

__global__ __launch_bounds__(256, 1) void fused_kernel(
    const int* __restrict__ c3_seq, const int* __restrict__ d_seq,
    const int* __restrict__ r_seq, const float* __restrict__ v_c3,
    const float* __restrict__ D_w, const float* __restrict__ v_d,
    const float* __restrict__ R_w, const float* __restrict__ W_ih,
    const float* __restrict__ W_hh, const float* __restrict__ b_ih,
    const float* __restrict__ b_hh,
    const float* __restrict__ l1_w1, const float* __restrict__ l1_b1,
    const float* __restrict__ l1_w2, const float* __restrict__ l1_b2,
    const float* __restrict__ l2_w1, const float* __restrict__ l2_b1,
    const float* __restrict__ l2_w2, const float* __restrict__ l2_b2,
    float* __restrict__ out_alpha, float* __restrict__ out_h,
    float* __restrict__ out_c3)
{
    // GRU path LDS
    __shared__ float l1T[64 * 64];                 // l1_w1 transposed (shared by 4 waves)
    __shared__ float gam_g[4][Sn];
    __shared__ int   r_g[4][Sn];
    __shared__ __align__(16) float pPart[4][Sn][4]; // deferred mlp1 partials
    // fill path LDS
    __shared__ float gam_f[Sn];
    __shared__ int   r_f[Sn];
    __shared__ int   c3_f[Sn];
    __shared__ float val_f[Sn];
    __shared__ int   succ_f[Sn];
    __shared__ int   root_f[Sn];
    __shared__ float wsA[64], wsB[64], wsC0[64], wsC1[64], wsW2[64];
    __shared__ float l2b2_sh;

    const int tid = threadIdx.x;
    const int bid = blockIdx.x;

    if (bid < GRUB) {
        // ======== GRU + mlp1 + alpha: 4 independent single-wave rows, NO in-loop barriers ========
        const int wid = tid >> 6;
        const int j   = tid & 63;           // lane owns h[j]
        const int b   = bid * 4 + wid;

        for (int i = j; i < Sn; i += 64) {
            gam_g[wid][i] = D_w[d_seq[b * Sn + i]];
            r_g[wid][i]   = r_seq[b * Sn + i];
        }
        if (wid == 0) {                      // wave0 stages l1_w1^T for everyone
            const float4* lr = (const float4*)(l1_w1 + (size_t)j * 64);
            #pragma unroll
            for (int k4 = 0; k4 < 16; ++k4) {
                float4 v = lr[k4];
                l1T[(4*k4+0)*64 + j] = v.x;
                l1T[(4*k4+1)*64 + j] = v.y;
                l1T[(4*k4+2)*64 + j] = v.z;
                l1T[(4*k4+3)*64 + j] = v.w;
            }
        }
        // W_hh rows j (r), 64+j (z), 128+j (n) in registers
        float wr[64], wz[64], wn[64];
        {
            const float4* r0 = (const float4*)(W_hh + (size_t)j * 64);
            const float4* r1 = (const float4*)(W_hh + (size_t)(64 + j) * 64);
            const float4* r2 = (const float4*)(W_hh + (size_t)(128 + j) * 64);
            #pragma unroll
            for (int k = 0; k < 16; ++k) {
                float4 a = r0[k], c = r1[k], d = r2[k];
                wr[4*k+0]=a.x; wr[4*k+1]=a.y; wr[4*k+2]=a.z; wr[4*k+3]=a.w;
                wz[4*k+0]=c.x; wz[4*k+1]=c.y; wz[4*k+2]=c.z; wz[4*k+3]=c.w;
                wn[4*k+0]=d.x; wn[4*k+1]=d.y; wn[4*k+2]=d.z; wn[4*k+3]=d.w;
            }
        }
        // fold xg: u = W_ih[rho,:64]@v_d ; w0/w1 = W_ih[rho,64:]@R_w[r] + b_ih[rho]
        float uu[3], ww0[3], ww1[3];
        #pragma unroll
        for (int g = 0; g < 3; ++g) {
            const int rho = g * 64 + j;
            const float4* rp  = (const float4*)(W_ih + (size_t)rho * 128);
            const float4* vd4 = (const float4*)v_d;
            const float4* q04 = (const float4*)R_w;
            const float4* q14 = (const float4*)(R_w + 64);
            float u = 0.f, w0 = 0.f, w1 = 0.f;
            #pragma unroll 4
            for (int k = 0; k < 16; ++k) {
                float4 a  = rp[k];
                float4 bb = rp[16 + k];
                float4 vd = vd4[k], q0 = q04[k], q1 = q14[k];
                u  += a.x*vd.x + a.y*vd.y + a.z*vd.z + a.w*vd.w;
                w0 += bb.x*q0.x + bb.y*q0.y + bb.z*q0.z + bb.w*q0.w;
                w1 += bb.x*q1.x + bb.y*q1.y + bb.z*q1.z + bb.w*q1.w;
            }
            float bih = b_ih[rho];
            uu[g] = u; ww0[g] = w0 + bih; ww1[g] = w1 + bih;
        }
        const float bhr = b_hh[j], bhz = b_hh[64 + j], bhn = b_hh[128 + j];
        const float l1b = l1_b1[j], l1w2v = l1_w2[j], l1b2c = l1_b2[0];
        __syncthreads();                     // single barrier (prologue only)

        float vh = 0.f;
        float hgr = bhr, hgz = bhz, hgn = bhn;   // W_hh@h0 + b_hh with h0=0
        float* outh_p = out_h + (size_t)b * Sn * 64 + j;

        for (int t = 0; t < Sn; ++t) {
            float gam = gam_g[wid][t];
            int   r   = r_g[wid][t];
            float xr = fmaf(gam, uu[0], r ? ww1[0] : ww0[0]);
            float xz = fmaf(gam, uu[1], r ? ww1[1] : ww0[1]);
            float xn = fmaf(gam, uu[2], r ? ww1[2] : ww0[2]);
            float rg = sigmf(xr + hgr);
            float zg = sigmf(xz + hgz);
            float e2 = __expf(2.f * (xn + rg * hgn));
            float ng = (e2 - 1.f) / (e2 + 1.f);          // tanh
            vh = (1.f - zg) * ng + zg * vh;
            outh_p[0] = vh; outh_p += 64;
            // four 64-dots via readlane broadcast (3 gate rows in regs, mlp1 row from l1T)
            float ar0=0,ar1=0,ar2=0,ar3=0, az0=0,az1=0,az2=0,az3=0;
            float an0=0,an1=0,an2=0,an3=0, am0=0,am1=0,am2=0,am3=0;
            #pragma unroll
            for (int k = 0; k < 64; k += 4) {
                float s0 = rlane(vh, k+0), s1 = rlane(vh, k+1);
                float s2 = rlane(vh, k+2), s3 = rlane(vh, k+3);
                ar0 = fmaf(wr[k+0], s0, ar0); ar1 = fmaf(wr[k+1], s1, ar1);
                ar2 = fmaf(wr[k+2], s2, ar2); ar3 = fmaf(wr[k+3], s3, ar3);
                az0 = fmaf(wz[k+0], s0, az0); az1 = fmaf(wz[k+1], s1, az1);
                az2 = fmaf(wz[k+2], s2, az2); az3 = fmaf(wz[k+3], s3, az3);
                an0 = fmaf(wn[k+0], s0, an0); an1 = fmaf(wn[k+1], s1, an1);
                an2 = fmaf(wn[k+2], s2, an2); an3 = fmaf(wn[k+3], s3, an3);
                am0 = fmaf(l1T[(k+0)*64 + j], s0, am0);
                am1 = fmaf(l1T[(k+1)*64 + j], s1, am1);
                am2 = fmaf(l1T[(k+2)*64 + j], s2, am2);
                am3 = fmaf(l1T[(k+3)*64 + j], s3, am3);
            }
            hgr = bhr + ((ar0+ar1)+(ar2+ar3));
            hgz = bhz + ((az0+az1)+(az2+az3));
            hgn = bhn + ((an0+an1)+(an2+an3));
            // mlp1 partial: relu + w2 weight per lane, reduce only to 16-lane groups (off critical path)
            float p = fmaxf(((am0+am1)+(am2+am3)) + l1b, 0.f) * l1w2v;
            p += __shfl_xor(p, 1);
            p += __shfl_xor(p, 2);
            p += __shfl_xor(p, 4);
            p += __shfl_xor(p, 8);
            if ((j & 15) == 0) pPart[wid][t][j >> 4] = p;
        }
        // deferred alpha chain (cheap, sequential, off the recurrence)
        float alpha = 0.f;
        for (int t = 0; t < Sn; ++t) {
            float4 pp = *(const float4*)&pPart[wid][t][0];
            float an = ((pp.x + pp.y) + (pp.z + pp.w)) + l1b2c;
            float gam = gam_g[wid][t];
            int   r   = r_g[wid][t];
            bool cond = (alpha - gam) >= 0.f;
            alpha = r ? (cond ? an : alpha) : (cond ? alpha : an);
            if (j == 0) out_alpha[b * Sn + t] = alpha;
        }
    } else {
        // ======== C3 chain + contiguous-stream forward-fill: one (row, t-half) ========
        const int fb   = bid - GRUB;
        const int b    = fb >> 1;
        const int half = fb & 1;
        if (tid < Sn) {
            gam_f[tid] = D_w[d_seq[b*Sn + tid]];
            r_f[tid]   = r_seq[b*Sn + tid];
            c3_f[tid]  = c3_seq[b*Sn + tid];
        }
        // collapsed mlp2 constants (vectorized)
        if (tid < 64) {
            const float4* row4 = (const float4*)(l2_w1 + (size_t)tid * 192);
            const float4* vc4  = (const float4*)v_c3;
            const float4* vd4  = (const float4*)v_d;
            const float4* q04  = (const float4*)R_w;
            const float4* q14  = (const float4*)(R_w + 64);
            float a2=0.f, b2=0.f, c0=0.f, c1=0.f;
            #pragma unroll 4
            for (int k = 0; k < 16; ++k) {
                float4 ra = row4[k], rb = row4[16+k], rc = row4[32+k];
                float4 vc = vc4[k], vd = vd4[k], q0 = q04[k], q1 = q14[k];
                a2 += ra.x*vc.x + ra.y*vc.y + ra.z*vc.z + ra.w*vc.w;
                b2 += rb.x*vd.x + rb.y*vd.y + rb.z*vd.z + rb.w*vd.w;
                c0 += rc.x*q0.x + rc.y*q0.y + rc.z*q0.z + rc.w*q0.w;
                c1 += rc.x*q1.x + rc.y*q1.y + rc.z*q1.z + rc.w*q1.w;
            }
            wsA[tid]  = a2;
            wsB[tid]  = b2;
            wsC0[tid] = c0 + l2_b1[tid];
            wsC1[tid] = c1 + l2_b1[tid];
            wsW2[tid] = l2_w2[tid];
        }
        if (tid == 0) l2b2_sh = l2_b2[0];
        __syncthreads();
        // successor / root links
        if (tid < Sn) {
            int c = c3_f[tid];
            int s = -1;
            for (int u = tid + 1; u < Sn; ++u)
                if (c3_f[u] == c) { s = u; break; }
            succ_f[tid] = s;
            int rt = 1;
            for (int u = 0; u < tid; ++u)
                if (c3_f[u] == c) { rt = 0; break; }
            root_f[tid] = rt;
        }
        __syncthreads();
        // walk dependency chains (16-lane groups)
        {
            const int g  = tid >> 4;
            const int l  = tid & 15;
            const int j0 = l * 4;
            float A0=wsA[j0],  A1=wsA[j0+1],  A2=wsA[j0+2],  A3=wsA[j0+3];
            float B0=wsB[j0],  B1=wsB[j0+1],  B2=wsB[j0+2],  B3=wsB[j0+3];
            float C00=wsC0[j0],C01=wsC0[j0+1],C02=wsC0[j0+2],C03=wsC0[j0+3];
            float C10=wsC1[j0],C11=wsC1[j0+1],C12=wsC1[j0+2],C13=wsC1[j0+3];
            float W0=wsW2[j0], W1=wsW2[j0+1], W2v=wsW2[j0+2],W3=wsW2[j0+3];
            float l2b2 = l2b2_sh;
            for (int t0 = g; t0 < Sn; t0 += 16) {
                if (!root_f[t0]) continue;
                float beta = 0.f;
                int t = t0;
                while (t >= 0) {
                    float gam = gam_f[t];
                    int   r   = r_f[t];
                    float s = W0*fmaxf(A0*beta + B0*gam + (r ? C10 : C00), 0.f)
                            + W1*fmaxf(A1*beta + B1*gam + (r ? C11 : C01), 0.f)
                            + W2v*fmaxf(A2*beta + B2*gam + (r ? C12 : C02), 0.f)
                            + W3*fmaxf(A3*beta + B3*gam + (r ? C13 : C03), 0.f);
                    s += __shfl_xor(s, 1, 16);
                    s += __shfl_xor(s, 2, 16);
                    s += __shfl_xor(s, 4, 16);
                    s += __shfl_xor(s, 8, 16);
                    beta = s + l2b2;
                    if (l == 0) val_f[t] = beta;
                    t = succ_f[t];
                }
            }
        }
        __syncthreads();
        // forward-fill: thread owns cols {k*1024 + tid*4} -> whole 16KB row stored
        // contiguously per t; block streams a sequential 1.6MB region.
        const int cA = tid*4, cB = 1024 + tid*4, cC = 2048 + tid*4, cD = 3072 + tid*4;
        float4 qA = make_float4(0.f,0.f,0.f,0.f), qB = qA, qC = qA, qD = qA;
        const int t0 = half * 100;
        for (int t = 0; t < t0; ++t) {       // pre-scan (no stores) for second half
            int cc = c3_f[t]; float v = val_f[t];
            UPD(qA, cA) UPD(qB, cB) UPD(qC, cC) UPD(qD, cD)
        }
        float* rowp = out_c3 + (size_t)b * Sn * NC3n + (size_t)t0 * NC3n;
        for (int t = t0; t < t0 + 100; ++t) {
            int cc = c3_f[t]; float v = val_f[t];
            UPD(qA, cA) UPD(qB, cB) UPD(qC, cC) UPD(qD, cD)
            *(float4*)(rowp + cA) = qA;
            *(float4*)(rowp + cB) = qB;
            *(float4*)(rowp + cC) = qC;
            if (tid < 232) *(float4*)(rowp + cD) = qD;   // cols 4000..4095 don't exist
            rowp += NC3n;
        }
    }
}

extern "C" void kernel_launch(void* const* d_in, const int* in_sizes, int n_in,
                              void* d_out, int out_size, void* d_ws, size_t ws_size,
                              hipStream_t stream)
{
    const int*   c3_seq = (const int*)  d_in[0];
    const int*   d_seq  = (const int*)  d_in[1];
    const int*   r_seq  = (const int*)  d_in[2];
    const float* v_c3   = (const float*)d_in[3];
    const float* D_w    = (const float*)d_in[4];
    const float* v_d    = (const float*)d_in[5];
    const float* R_w    = (const float*)d_in[6];
    const float* W_ih   = (const float*)d_in[7];
    const float* W_hh   = (const float*)d_in[8];
    const float* b_ih   = (const float*)d_in[9];
    const float* b_hh   = (const float*)d_in[10];
    const float* l1_w1  = (const float*)d_in[11];
    const float* l1_b1  = (const float*)d_in[12];
    const float* l1_w2  = (const float*)d_in[13];
    const float* l1_b2  = (const float*)d_in[14];
    const float* l2_w1  = (const float*)d_in[15];
    const float* l2_b1  = (const float*)d_in[16];
    const float* l2_w2  = (const float*)d_in[17];
    const float* l2_b2  = (const float*)d_in[18];

    float* out_alpha = (float*)d_out;
    float* out_h     = out_alpha + Bn*Sn;
    float* out_c3    = out_h + (size_t)Bn*Sn*64;

    fused_kernel<<<GRUB + FILLB, 256, 0, stream>>>(
        c3_seq, d_seq, r_seq, v_c3, D_w, v_d, R_w, W_ih, W_hh, b_ih, b_hh,
        l1_w1, l1_b1, l1_w2, l1_b2, l2_w1, l2_b1, l2_w2, l2_b2,
        out_alpha, out_h, out_c3);
}

// Round 7
// 189.272 us; speedup vs baseline: 1.3465x; 1.3465x over previous
//
#include <hip/hip_runtime.h>
#include <math.h>

#define Bn 128
#define Sn 200
#define NC3n 4000
#define GRUB Bn                 // 128 GRU blocks (1 row each)
#define FILLB (Bn * 4)          // (b, quarter): 512 fill blocks, 50 rows each

__device__ __forceinline__ float sigmf(float x) { return 1.f / (1.f + __expf(-x)); }
__device__ __forceinline__ float rlane(float v, int k) {
    return __int_as_float(__builtin_amdgcn_readlane(__float_as_int(v), k));
}

#define UPD(q, cbase) { int d = cc - (cbase); if ((unsigned)d < 4u) { \
    q.x = (d==0)?v:q.x; q.y = (d==1)?v:q.y; q.z = (d==2)?v:q.z; q.w = (d==3)?v:q.w; } }

struct GruLds {
    float h_hist[Sn * 64];      // 51200 B, 16B-aligned offsets below
    float pPart[Sn][4];         // mlp1 16-lane partials
    float u[192], w0[192], w1[192];
    float hg[2][192];           // ping-pong W_hh@h + b_hh
    float gam[Sn];
    float alpha_arr[Sn];
    int   r[Sn];
};
struct FillLds {
    float gam[Sn]; float val[Sn];
    int   r[Sn];   int c3[Sn]; int succ[Sn]; int root[Sn];
    float A[64], Bv[64], C0[64], C1[64], W2[64];
    float l2b2;
};

__global__ __launch_bounds__(256) void fused_kernel(
    const int* __restrict__ c3_seq, const int* __restrict__ d_seq,
    const int* __restrict__ r_seq, const float* __restrict__ v_c3,
    const float* __restrict__ D_w, const float* __restrict__ v_d,
    const float* __restrict__ R_w, const float* __restrict__ W_ih,
    const float* __restrict__ W_hh, const float* __restrict__ b_ih,
    const float* __restrict__ b_hh,
    const float* __restrict__ l1_w1, const float* __restrict__ l1_b1,
    const float* __restrict__ l1_w2, const float* __restrict__ l1_b2,
    const float* __restrict__ l2_w1, const float* __restrict__ l2_b1,
    const float* __restrict__ l2_w2, const float* __restrict__ l2_b2,
    float* __restrict__ out_alpha, float* __restrict__ out_h,
    float* __restrict__ out_c3)
{
    __shared__ __align__(16) union { GruLds g; FillLds f; } S;

    const int tid = threadIdx.x;
    const int bid = blockIdx.x;

    if (bid < GRUB) {
        // ===== GRU + mlp1 + alpha: 1 row, 4 waves, 1 barrier/step, no VMEM in loop =====
        const int b   = bid;
        const int wid = tid >> 6;
        const int j   = tid & 63;

        if (tid < Sn) {
            S.g.gam[tid] = D_w[d_seq[b * Sn + tid]];
            S.g.r[tid]   = r_seq[b * Sn + tid];
        }
        // fold xg: u = W_ih[rho,:64]@v_d ; w0/w1 = W_ih[rho,64:]@R_w[r] + b_ih[rho]
        if (tid < 192) {
            const float4* rp  = (const float4*)(W_ih + (size_t)tid * 128);
            const float4* vd4 = (const float4*)v_d;
            const float4* q04 = (const float4*)R_w;
            const float4* q14 = (const float4*)(R_w + 64);
            float u = 0.f, w0 = 0.f, w1 = 0.f;
            #pragma unroll 4
            for (int k = 0; k < 16; ++k) {
                float4 a  = rp[k];
                float4 bb = rp[16 + k];
                float4 vd = vd4[k], q0 = q04[k], q1 = q14[k];
                u  += a.x*vd.x + a.y*vd.y + a.z*vd.z + a.w*vd.w;
                w0 += bb.x*q0.x + bb.y*q0.y + bb.z*q0.z + bb.w*q0.w;
                w1 += bb.x*q1.x + bb.y*q1.y + bb.z*q1.z + bb.w*q1.w;
            }
            float bih = b_ih[tid];
            S.g.u[tid]  = u;
            S.g.w0[tid] = w0 + bih;
            S.g.w1[tid] = w1 + bih;
        }
        // wave g owns one 64-float weight row per lane: Wr/Wz/Wn rows for g<3, l1_w1 for g==3
        float w[64];
        {
            const float* src = (wid < 3) ? (W_hh + (size_t)(wid * 64 + j) * 64)
                                         : (l1_w1 + (size_t)j * 64);
            const float4* s4 = (const float4*)src;
            #pragma unroll
            for (int k = 0; k < 16; ++k) {
                float4 v = s4[k];
                w[4*k+0]=v.x; w[4*k+1]=v.y; w[4*k+2]=v.z; w[4*k+3]=v.w;
            }
        }
        float bown = 0.f, l1b = 0.f, l1w2v = 0.f;
        if (wid < 3) {
            bown = b_hh[wid * 64 + j];
            S.g.hg[0][wid * 64 + j] = bown;     // h0 = 0 -> hg(t=0) = b_hh
        } else {
            l1b = l1_b1[j]; l1w2v = l1_w2[j];
        }
        const float l1b2c = l1_b2[0];
        __syncthreads();

        // per-lane xg constants (all waves identical)
        const float uj  = S.g.u[j],  u1  = S.g.u[64+j],  u2  = S.g.u[128+j];
        const float w00 = S.g.w0[j], w01 = S.g.w0[64+j], w02 = S.g.w0[128+j];
        const float w10 = S.g.w1[j], w11 = S.g.w1[64+j], w12 = S.g.w1[128+j];

        float vh = 0.f;
        for (int t = 0; t < Sn; ++t) {
            const int buf = t & 1;
            float gam = S.g.gam[t];
            int   r   = S.g.r[t];
            float hr = S.g.hg[buf][j], hz = S.g.hg[buf][64+j], hn = S.g.hg[buf][128+j];
            // gates (redundant in all 4 waves -> bit-identical vh)
            float rg = sigmf(fmaf(gam, uj, r ? w10 : w00) + hr);
            float zg = sigmf(fmaf(gam, u1, r ? w11 : w01) + hz);
            float e2 = __expf(2.f * (fmaf(gam, u2, r ? w12 : w02) + rg * hn));
            float ng = (e2 - 1.f) / (e2 + 1.f);      // tanh
            vh = (1.f - zg) * ng + zg * vh;
            // own 64-dot via readlane broadcast
            float a0=0.f, a1=0.f, a2=0.f, a3=0.f;
            #pragma unroll
            for (int k = 0; k < 64; k += 4) {
                a0 = fmaf(w[k+0], rlane(vh, k+0), a0);
                a1 = fmaf(w[k+1], rlane(vh, k+1), a1);
                a2 = fmaf(w[k+2], rlane(vh, k+2), a2);
                a3 = fmaf(w[k+3], rlane(vh, k+3), a3);
            }
            float dot = (a0 + a1) + (a2 + a3);
            if (wid < 3) {
                S.g.hg[buf ^ 1][wid * 64 + j] = bown + dot;
            } else {
                float p = fmaxf(dot + l1b, 0.f) * l1w2v;
                p += __shfl_xor(p, 1);
                p += __shfl_xor(p, 2);
                p += __shfl_xor(p, 4);
                p += __shfl_xor(p, 8);
                if ((j & 15) == 0) S.g.pPart[t][j >> 4] = p;
                S.g.h_hist[t * 64 + j] = vh;
            }
            __syncthreads();
        }
        // deferred alpha chain (LDS only)
        if (tid == 0) {
            float alpha = 0.f;
            for (int t = 0; t < Sn; ++t) {
                float4 pp = *(const float4*)&S.g.pPart[t][0];
                float an = ((pp.x + pp.y) + (pp.z + pp.w)) + l1b2c;
                float gam = S.g.gam[t];
                int   r   = S.g.r[t];
                bool cond = (alpha - gam) >= 0.f;
                alpha = r ? (cond ? an : alpha) : (cond ? alpha : an);
                S.g.alpha_arr[t] = alpha;
            }
        }
        __syncthreads();
        // bulk copy-out (coalesced float4 streams)
        {
            float4* oh = (float4*)(out_h + (size_t)b * Sn * 64);
            const float4* hh = (const float4*)S.g.h_hist;
            for (int i = tid; i < Sn * 16; i += 256) oh[i] = hh[i];
            float4* oa = (float4*)(out_alpha + b * Sn);
            const float4* aa = (const float4*)S.g.alpha_arr;
            for (int i = tid; i < Sn / 4; i += 256) oa[i] = aa[i];
        }
    } else {
        // ===== C3 chain + contiguous forward-fill: one (row, quarter) =====
        const int fb = bid - GRUB;
        const int b  = fb >> 2;
        const int qt = fb & 3;
        if (tid < Sn) {
            S.f.gam[tid] = D_w[d_seq[b*Sn + tid]];
            S.f.r[tid]   = r_seq[b*Sn + tid];
            S.f.c3[tid]  = c3_seq[b*Sn + tid];
        }
        if (tid < 64) {
            const float4* row4 = (const float4*)(l2_w1 + (size_t)tid * 192);
            const float4* vc4  = (const float4*)v_c3;
            const float4* vd4  = (const float4*)v_d;
            const float4* q04  = (const float4*)R_w;
            const float4* q14  = (const float4*)(R_w + 64);
            float a2=0.f, b2=0.f, c0=0.f, c1=0.f;
            #pragma unroll 4
            for (int k = 0; k < 16; ++k) {
                float4 ra = row4[k], rb = row4[16+k], rc = row4[32+k];
                float4 vc = vc4[k], vd = vd4[k], q0 = q04[k], q1 = q14[k];
                a2 += ra.x*vc.x + ra.y*vc.y + ra.z*vc.z + ra.w*vc.w;
                b2 += rb.x*vd.x + rb.y*vd.y + rb.z*vd.z + rb.w*vd.w;
                c0 += rc.x*q0.x + rc.y*q0.y + rc.z*q0.z + rc.w*q0.w;
                c1 += rc.x*q1.x + rc.y*q1.y + rc.z*q1.z + rc.w*q1.w;
            }
            S.f.A[tid]  = a2;
            S.f.Bv[tid] = b2;
            S.f.C0[tid] = c0 + l2_b1[tid];
            S.f.C1[tid] = c1 + l2_b1[tid];
            S.f.W2[tid] = l2_w2[tid];
        }
        if (tid == 0) S.f.l2b2 = l2_b2[0];
        __syncthreads();
        if (tid < Sn) {
            int c = S.f.c3[tid];
            int s = -1;
            for (int u = tid + 1; u < Sn; ++u)
                if (S.f.c3[u] == c) { s = u; break; }
            S.f.succ[tid] = s;
            int rt = 1;
            for (int u = 0; u < tid; ++u)
                if (S.f.c3[u] == c) { rt = 0; break; }
            S.f.root[tid] = rt;
        }
        __syncthreads();
        {   // chain walk, 16-lane groups
            const int g  = tid >> 4;
            const int l  = tid & 15;
            const int j0 = l * 4;
            float A0=S.f.A[j0],  A1=S.f.A[j0+1],  A2=S.f.A[j0+2],  A3=S.f.A[j0+3];
            float B0=S.f.Bv[j0], B1=S.f.Bv[j0+1], B2=S.f.Bv[j0+2], B3=S.f.Bv[j0+3];
            float C00=S.f.C0[j0],C01=S.f.C0[j0+1],C02=S.f.C0[j0+2],C03=S.f.C0[j0+3];
            float C10=S.f.C1[j0],C11=S.f.C1[j0+1],C12=S.f.C1[j0+2],C13=S.f.C1[j0+3];
            float W0=S.f.W2[j0], W1=S.f.W2[j0+1], W2v=S.f.W2[j0+2],W3=S.f.W2[j0+3];
            float l2b2 = S.f.l2b2;
            for (int t0 = g; t0 < Sn; t0 += 16) {
                if (!S.f.root[t0]) continue;
                float beta = 0.f;
                int t = t0;
                while (t >= 0) {
                    float gam = S.f.gam[t];
                    int   r   = S.f.r[t];
                    float s = W0*fmaxf(A0*beta + B0*gam + (r ? C10 : C00), 0.f)
                            + W1*fmaxf(A1*beta + B1*gam + (r ? C11 : C01), 0.f)
                            + W2v*fmaxf(A2*beta + B2*gam + (r ? C12 : C02), 0.f)
                            + W3*fmaxf(A3*beta + B3*gam + (r ? C13 : C03), 0.f);
                    s += __shfl_xor(s, 1, 16);
                    s += __shfl_xor(s, 2, 16);
                    s += __shfl_xor(s, 4, 16);
                    s += __shfl_xor(s, 8, 16);
                    beta = s + l2b2;
                    if (l == 0) S.f.val[t] = beta;
                    t = S.f.succ[t];
                }
            }
        }
        __syncthreads();
        // forward-fill 50 rows x 16KB, contiguous; unroll-2 with distinct store temps
        const int cA = tid*4, cB = 1024 + tid*4, cC = 2048 + tid*4, cD = 3072 + tid*4;
        float4 qA = make_float4(0.f,0.f,0.f,0.f), qB = qA, qC = qA, qD = qA;
        const int t0 = qt * 50;
        for (int t = 0; t < t0; ++t) {          // pre-scan (no stores)
            int cc = S.f.c3[t]; float v = S.f.val[t];
            UPD(qA, cA) UPD(qB, cB) UPD(qC, cC) UPD(qD, cD)
        }
        float* rowp = out_c3 + (size_t)b * Sn * NC3n + (size_t)t0 * NC3n;
        const bool doD = (tid < 232);
        for (int t = t0; t < t0 + 50; t += 2) {
            {
                int cc = S.f.c3[t]; float v = S.f.val[t];
                UPD(qA, cA) UPD(qB, cB) UPD(qC, cC) UPD(qD, cD)
                float4 sA = qA, sB = qB, sC = qC, sD = qD;
                *(float4*)(rowp + cA) = sA;
                *(float4*)(rowp + cB) = sB;
                *(float4*)(rowp + cC) = sC;
                if (doD) *(float4*)(rowp + cD) = sD;
                rowp += NC3n;
            }
            {
                int cc = S.f.c3[t+1]; float v = S.f.val[t+1];
                UPD(qA, cA) UPD(qB, cB) UPD(qC, cC) UPD(qD, cD)
                float4 uA = qA, uB = qB, uC = qC, uD = qD;
                *(float4*)(rowp + cA) = uA;
                *(float4*)(rowp + cB) = uB;
                *(float4*)(rowp + cC) = uC;
                if (doD) *(float4*)(rowp + cD) = uD;
                rowp += NC3n;
            }
        }
    }
}

extern "C" void kernel_launch(void* const* d_in, const int* in_sizes, int n_in,
                              void* d_out, int out_size, void* d_ws, size_t ws_size,
                              hipStream_t stream)
{
    const int*   c3_seq = (const int*)  d_in[0];
    const int*   d_seq  = (const int*)  d_in[1];
    const int*   r_seq  = (const int*)  d_in[2];
    const float* v_c3   = (const float*)d_in[3];
    const float* D_w    = (const float*)d_in[4];
    const float* v_d    = (const float*)d_in[5];
    const float* R_w    = (const float*)d_in[6];
    const float* W_ih   = (const float*)d_in[7];
    const float* W_hh   = (const float*)d_in[8];
    const float* b_ih   = (const float*)d_in[9];
    const float* b_hh   = (const float*)d_in[10];
    const float* l1_w1  = (const float*)d_in[11];
    const float* l1_b1  = (const float*)d_in[12];
    const float* l1_w2  = (const float*)d_in[13];
    const float* l1_b2  = (const float*)d_in[14];
    const float* l2_w1  = (const float*)d_in[15];
    const float* l2_b1  = (const float*)d_in[16];
    const float* l2_w2  = (const float*)d_in[17];
    const float* l2_b2  = (const float*)d_in[18];

    float* out_alpha = (float*)d_out;
    float* out_h     = out_alpha + Bn*Sn;
    float* out_c3    = out_h + (size_t)Bn*Sn*64;

    fused_kernel<<<GRUB + FILLB, 256, 0, stream>>>(
        c3_seq, d_seq, r_seq, v_c3, D_w, v_d, R_w, W_ih, W_hh, b_ih, b_hh,
        l1_w1, l1_b1, l1_w2, l1_b2, l2_w1, l2_b1, l2_w2, l2_b2,
        out_alpha, out_h, out_c3);
}